// Round 1
// 1521.200 us; speedup vs baseline: 1.1999x; 1.1999x over previous
//
#include <hip/hip_runtime.h>
#include <math.h>

#define N_NODES 40000
#define N_EDGES 640000
#define IN_DIM  128
#define HD      128   // H*D
#define NHEADS  8
#define DHEAD   16
#define CAP     64    // per-dst edge bucket capacity (Poisson(16): P(deg>64)~3e-22)

// ---------------------------------------------------------------------------
// Kernel A: Q/K/V node projections.  16 nodes per block, 256 threads.
// thread t: col = t&127, g = t>>7 handles nodes g*8 .. g*8+7 of the tile.
// ---------------------------------------------------------------------------
__global__ __launch_bounds__(256) void qkv_kernel(
    const float* __restrict__ h,
    const float* __restrict__ Wq, const float* __restrict__ bq,
    const float* __restrict__ Wk, const float* __restrict__ bk,
    const float* __restrict__ Wv, const float* __restrict__ bv,
    float* __restrict__ Q, float* __restrict__ K, float* __restrict__ V)
{
    __shared__ __align__(16) float hs[16][128];   // 8 KB
    const int t   = threadIdx.x;
    const int col = t & 127;
    const int g   = t >> 7;                 // 0/1
    const int n0  = blockIdx.x * 16;

    // stage 16 h-rows (2048 floats = 512 float4)
    {
        const float4* sp = (const float4*)(h + (size_t)n0 * IN_DIM);
        float4* dp = (float4*)(&hs[0][0]);
        dp[t]       = sp[t];
        dp[t + 256] = sp[t + 256];
    }
    __syncthreads();

    float accq[8], acck[8], accv[8];
#pragma unroll
    for (int i = 0; i < 8; ++i) { accq[i] = 0.f; acck[i] = 0.f; accv[i] = 0.f; }

    for (int k0 = 0; k0 < IN_DIM; k0 += 4) {
        float wq[4], wk[4], wv[4];
#pragma unroll
        for (int kk = 0; kk < 4; ++kk) {
            wq[kk] = Wq[(size_t)(k0 + kk) * HD + col];
            wk[kk] = Wk[(size_t)(k0 + kk) * HD + col];
            wv[kk] = Wv[(size_t)(k0 + kk) * HD + col];
        }
#pragma unroll
        for (int i = 0; i < 8; ++i) {
            const float4 h4 = *(const float4*)(&hs[g * 8 + i][k0]);
            accq[i] += h4.x * wq[0] + h4.y * wq[1] + h4.z * wq[2] + h4.w * wq[3];
            acck[i] += h4.x * wk[0] + h4.y * wk[1] + h4.z * wk[2] + h4.w * wk[3];
            accv[i] += h4.x * wv[0] + h4.y * wv[1] + h4.z * wv[2] + h4.w * wv[3];
        }
    }

    const float bqc = bq[col], bkc = bk[col], bvc = bv[col];
#pragma unroll
    for (int i = 0; i < 8; ++i) {
        const size_t n = (size_t)(n0 + g * 8 + i);
        Q[n * HD + col] = accq[i] + bqc;
        K[n * HD + col] = acck[i] + bkc;
        V[n * HD + col] = accv[i] + bvc;
    }
}

// ---------------------------------------------------------------------------
// Kernel S: bucket edges by destination.  pos = cnt[d]++ ; list[d*CAP+pos]=eid
// 640K int atomics to 40K counters (avg 16 hits each) — cheap.
// ---------------------------------------------------------------------------
__global__ __launch_bounds__(256) void scatter_kernel(
    const int* __restrict__ dst, int* __restrict__ cnt, int* __restrict__ list)
{
    const int eid = blockIdx.x * 256 + threadIdx.x;
    const int d = dst[eid];
    const int pos = atomicAdd(&cnt[d], 1);
    if (pos < CAP) list[d * CAP + pos] = eid;
}

// ---------------------------------------------------------------------------
// Kernel B: fused edge kernel.  32 edges per block, 256 threads.
// thread t: cg = t&31 -> cols 4cg..4cg+3 ; eg = t>>5 -> edges eg*4..eg*4+3.
// pe = e @ We + be with We staged in LDS (two 64-row k-phases),
// then score = K[src]*Q[dst]*pe/4 -> e_out, and per-head att -> att buffer.
// NO atomics, NO V read — pure streaming now.
// ---------------------------------------------------------------------------
#define TE 32
__global__ __launch_bounds__(256) void edge_kernel(
    const float* __restrict__ e,
    const int* __restrict__ src, const int* __restrict__ dst,
    const float* __restrict__ We, const float* __restrict__ be,
    const float* __restrict__ Q, const float* __restrict__ K,
    float* __restrict__ e_out,   // d_out + N*128
    float* __restrict__ att)     // ws, [E, 8]
{
    __shared__ __align__(16) float we_s[64][132];  // one k-phase, +4 pad: 33 KB
    __shared__ __align__(16) float es[TE][128];    // 16 KB

    const int t  = threadIdx.x;
    const int cg = t & 31;     // col group
    const int eg = t >> 5;     // edge group
    const int e0 = blockIdx.x * TE;

    // stage 32 e-rows (4096 floats = 1024 float4)
    {
        const float4* sp = (const float4*)(e + (size_t)e0 * IN_DIM);
        float4* dp = (float4*)(&es[0][0]);
#pragma unroll
        for (int i = 0; i < 4; ++i) dp[t + 256 * i] = sp[t + 256 * i];
    }

    float acc[4][4];
#pragma unroll
    for (int i = 0; i < 4; ++i)
#pragma unroll
        for (int c = 0; c < 4; ++c) acc[i][c] = 0.f;

    for (int phase = 0; phase < 2; ++phase) {
        __syncthreads();   // protect we_s reuse (and es on phase 0)
        // stage 64 rows of We: 8192 floats = 2048 float4, 8 per thread
        {
            const float4* sp = (const float4*)(We + (size_t)phase * 64 * HD);
#pragma unroll
            for (int i = 0; i < 8; ++i) {
                const int idx = t + 256 * i;   // float4 index
                const int r   = idx >> 5;      // 32 float4 per row
                const int c4  = idx & 31;
                *(float4*)(&we_s[r][c4 * 4]) = sp[idx];
            }
        }
        __syncthreads();

        const int kbase = phase * 64;
        for (int k0 = 0; k0 < 64; k0 += 4) {
            float4 w0 = *(const float4*)(&we_s[k0 + 0][cg * 4]);
            float4 w1 = *(const float4*)(&we_s[k0 + 1][cg * 4]);
            float4 w2 = *(const float4*)(&we_s[k0 + 2][cg * 4]);
            float4 w3 = *(const float4*)(&we_s[k0 + 3][cg * 4]);
#pragma unroll
            for (int i = 0; i < 4; ++i) {
                const float4 ev = *(const float4*)(&es[eg * 4 + i][kbase + k0]);
                acc[i][0] += ev.x * w0.x + ev.y * w1.x + ev.z * w2.x + ev.w * w3.x;
                acc[i][1] += ev.x * w0.y + ev.y * w1.y + ev.z * w2.y + ev.w * w3.y;
                acc[i][2] += ev.x * w0.z + ev.y * w1.z + ev.z * w2.z + ev.w * w3.z;
                acc[i][3] += ev.x * w0.w + ev.y * w1.w + ev.z * w2.w + ev.w * w3.w;
            }
        }
    }

    const float4 be4 = *(const float4*)(&be[cg * 4]);

#pragma unroll
    for (int i = 0; i < 4; ++i) {
        const int eid = e0 + eg * 4 + i;
        const int s = src[eid];
        const int d = dst[eid];
        const float4 K4 = *(const float4*)(&K[(size_t)s * HD + cg * 4]);
        const float4 Q4 = *(const float4*)(&Q[(size_t)d * HD + cg * 4]);

        float4 sc;
        sc.x = K4.x * Q4.x * 0.25f * (acc[i][0] + be4.x);
        sc.y = K4.y * Q4.y * 0.25f * (acc[i][1] + be4.y);
        sc.z = K4.z * Q4.z * 0.25f * (acc[i][2] + be4.z);
        sc.w = K4.w * Q4.w * 0.25f * (acc[i][3] + be4.w);

        *(float4*)(&e_out[(size_t)eid * HD + cg * 4]) = sc;

        // per-head attention: sum over the head's 16 cols = 4 adjacent lanes
        float part = sc.x + sc.y + sc.z + sc.w;
        part += __shfl_xor(part, 1);
        part += __shfl_xor(part, 2);
        if ((cg & 3) == 0) {
            const float a = __expf(fminf(fmaxf(part, -5.f), 5.f));
            att[(size_t)eid * NHEADS + (cg >> 2)] = a;
        }
    }
}

// ---------------------------------------------------------------------------
// Kernel G: per-node gather-aggregate.  1 wave per node, lane owns 2 cols.
// h_out[n] = sum_e att[e,h] * V[src[e]] / (sum_e att[e,h] + 1e-6)
// V (20 MB) is L3-resident; V-row reads are coalesced 512B bursts.
// ---------------------------------------------------------------------------
__global__ __launch_bounds__(256) void gather_kernel(
    const int* __restrict__ cnt, const int* __restrict__ list,
    const int* __restrict__ src, const float* __restrict__ att,
    const float* __restrict__ V, float* __restrict__ h_out)
{
    const int t    = threadIdx.x;
    const int lane = t & 63;
    const int node = blockIdx.x * 4 + (t >> 6);
    const int head = lane >> 3;          // col pair (2*lane, 2*lane+1) -> head
    const int deg  = min(cnt[node], CAP);
    const int base = node * CAP;

    float2 acc = {0.f, 0.f};
    float  zz  = 0.f;
    for (int j = 0; j < deg; ++j) {
        const int eid = list[base + j];
        const int s   = src[eid];
        const float a = att[(size_t)eid * NHEADS + head];
        const float2 v = *(const float2*)(&V[(size_t)s * HD + 2 * lane]);
        acc.x += v.x * a;
        acc.y += v.y * a;
        zz    += a;
    }
    const float inv = 1.f / (zz + 1e-6f);
    float2 r = {acc.x * inv, acc.y * inv};
    *(float2*)(&h_out[(size_t)node * HD + 2 * lane]) = r;
}

// ---------------------------------------------------------------------------
extern "C" void kernel_launch(void* const* d_in, const int* in_sizes, int n_in,
                              void* d_out, int out_size, void* d_ws, size_t ws_size,
                              hipStream_t stream)
{
    const float* h  = (const float*)d_in[0];
    const float* e  = (const float*)d_in[1];
    const int*   src = (const int*)d_in[2];
    const int*   dst = (const int*)d_in[3];
    const float* Wq = (const float*)d_in[4];
    const float* bq = (const float*)d_in[5];
    const float* Wk = (const float*)d_in[6];
    const float* bk = (const float*)d_in[7];
    const float* Wv = (const float*)d_in[8];
    const float* bv = (const float*)d_in[9];
    const float* We = (const float*)d_in[10];
    const float* be = (const float*)d_in[11];

    float* out   = (float*)d_out;
    float* h_out = out;                               // N*128 floats
    float* e_out = out + (size_t)N_NODES * HD;        // E*128 floats

    // workspace layout (~92.3 MB):
    //   Q,K,V: 3 * N*128 f32 (61.4 MB) | att: E*8 f32 (20.5 MB)
    //   cnt: N i32 (0.16 MB)           | list: N*CAP i32 (10.2 MB)
    float* ws  = (float*)d_ws;
    float* Q   = ws;
    float* K   = Q + (size_t)N_NODES * HD;
    float* V   = K + (size_t)N_NODES * HD;
    float* att = V + (size_t)N_NODES * HD;
    int*   cnt  = (int*)(att + (size_t)N_EDGES * NHEADS);
    int*   list = cnt + N_NODES;

    hipMemsetAsync(cnt, 0, N_NODES * sizeof(int), stream);

    scatter_kernel<<<N_EDGES / 256, 256, 0, stream>>>(dst, cnt, list);
    qkv_kernel<<<N_NODES / 16, 256, 0, stream>>>(h, Wq, bq, Wk, bk, Wv, bv, Q, K, V);
    edge_kernel<<<N_EDGES / TE, 256, 0, stream>>>(e, src, dst, We, be, Q, K,
                                                  e_out, att);
    gather_kernel<<<N_NODES / 4, 256, 0, stream>>>(cnt, list, src, att, V, h_out);
}